// Round 4
// baseline (123.444 us; speedup 1.0000x reference)
//
#include <hip/hip_runtime.h>

#define N_NODES 10000
#define N_EDGES 640000
#define D 128
#define NQ (N_EDGES / 4)      // 160000 edge quads

#define NCHUNK 256            // scatter chunks (= scatter blocks)
#define QPC (NQ / NCHUNK)     // 625 quads per chunk (exact)
#define GEMM_BLOCKS 157       // 64 nodes per block (MFMA)
#define GRID1 (NCHUNK + GEMM_BLOCKS)   // 413
#define NBUCK 79              // bucket = row >> 7
#define CCAP 96               // per (bucket,chunk) cell cap: mean 31.6, +11 sigma
#define SLOTS (NCHUNK * CCAP) // 24576 slots per bucket
#define SPILLCAP 2500         // max edges a chunk could spill (all of them)
#define CAP2 128              // per-row queue cap (mean 64, +8 sigma; slow path below)
#define QPAD2 144             // CAP2 + 16 zero-pad
#define LSTR 136              // LDS row stride in ushorts (272B)

typedef unsigned int uint32;
typedef unsigned short u16;
using short8 = __attribute__((ext_vector_type(8))) short;
using f32x4  = __attribute__((ext_vector_type(4))) float;

__device__ __forceinline__ uint32 f2bf_bits(float f) {
    uint32 u = __float_as_uint(f);
    return (u + 0x7FFFu + ((u >> 16) & 1u)) >> 16;   // RNE bf16 bits
}
__device__ __forceinline__ uint32 pack2(float lo, float hi) {
    return f2bf_bits(lo) | (f2bf_bits(hi) << 16);
}

// R12: 2 dispatches total, zero global atomics, zero pre-zeroed state.
// R10 (scatter TLP) and R11 (atomic removal) were both null => scatter
// internals are not the pole; remaining untested suspect is per-dispatch
// fixed cost (launch gap + L2 wb/inv right after the 256MB poison fill).
// Chunk-private placement: scatter block sb owns bstore[b][sb][.] per
// bucket; counts live in LDS and are written unconditionally to
// cnts[b][sb] (overwrites poison => no memset dispatch needed).
// Blocks [0,256): scatter (start first). Blocks [256,413): MFMA GEMM.
__global__ __launch_bounds__(256, 4) void gemm_scatter_kernel(
    const float* __restrict__ x, const float* __restrict__ w,
    const int* __restrict__ row, const int* __restrict__ col,
    const float* __restrict__ val,
    uint32* __restrict__ h2, int* __restrict__ cnts,
    int* __restrict__ spillcnt, uint2* __restrict__ bstore,
    uint2* __restrict__ spill)
{
    __shared__ __align__(16) u16 Ws[128 * LSTR];   // 34816 B (scatter aliases)
    const int t = threadIdx.x;

    if (blockIdx.x < NCHUNK) {
        // ---- chunk scatter: single pass, LDS counters only ----
        int* lcnt = (int*)Ws;             // [0..78] bucket counts, [95] spill
        if (t < 96) lcnt[t] = 0;
        __syncthreads();

        const int sb = blockIdx.x;
        const int4*   row4 = (const int4*)row;
        const int4*   col4 = (const int4*)col;
        const float4* val4 = (const float4*)val;
        const int i0 = sb * QPC;
        for (int i = i0 + t; i < i0 + QPC; i += 256) {
            int4 r = row4[i]; int4 c = col4[i]; float4 v = val4[i];
            #pragma unroll
            for (int e = 0; e < 4; ++e) {
                int rr = (e == 0) ? r.x : (e == 1) ? r.y : (e == 2) ? r.z : r.w;
                int cc = (e == 0) ? c.x : (e == 1) ? c.y : (e == 2) ? c.z : c.w;
                float vv = (e == 0) ? v.x : (e == 1) ? v.y : (e == 2) ? v.z : v.w;
                uint32 rc = (uint32)cc | (f2bf_bits(vv) << 16);
                int b = rr >> 7;
                int k = atomicAdd(&lcnt[b], 1);            // LDS only
                if (k < CCAP)
                    bstore[(size_t)(b * NCHUNK + sb) * CCAP + k] =
                        make_uint2(rc, (uint32)rr);
                else {                                     // +11 sigma, ~never
                    int ks = atomicAdd(&lcnt[95], 1);
                    spill[(size_t)sb * SPILLCAP + ks] = make_uint2(rc, (uint32)rr);
                }
            }
        }
        __syncthreads();
        if (t < NBUCK) {
            int c = lcnt[t];
            cnts[t * NCHUNK + sb] = (c < CCAP) ? c : CCAP;  // unconditional
        }
        if (t == 96) spillcnt[sb] = lcnt[95];               // unconditional
    } else {
        // ---- MFMA GEMM: 64 rows/block, 4 waves x 16 rows x 128 cols.
        // A direct global->reg; W staged col-major in LDS (float4 loads).
        // C/D: col=lane&15, row=quad*4+reg (HW-verified).
        const int g = blockIdx.x - NCHUNK;
        const int lane = t & 63;
        const int wid  = t >> 6;
        const int q = lane >> 4, cl = lane & 15;

        const float4* w4 = (const float4*)w;
        #pragma unroll
        for (int i = 0; i < 8; ++i) {                 // stage W^T (128x128)
            int lin = t + i * 256;                    // m(k-pair) x qc(col-quad)
            int m  = lin >> 5;
            int qc = lin & 31;
            float4 r0 = w4[(2 * m) * 32 + qc];        // row 2m, cols 4qc..4qc+3
            float4 r1 = w4[(2 * m + 1) * 32 + qc];
            int c = qc * 4;
            *(uint32*)&Ws[(c + 0) * LSTR + 2 * m] = pack2(r0.x, r1.x);
            *(uint32*)&Ws[(c + 1) * LSTR + 2 * m] = pack2(r0.y, r1.y);
            *(uint32*)&Ws[(c + 2) * LSTR + 2 * m] = pack2(r0.z, r1.z);
            *(uint32*)&Ws[(c + 3) * LSTR + 2 * m] = pack2(r0.w, r1.w);
        }

        int gr = g * 64 + wid * 16 + cl;              // A-fragment row
        if (gr >= N_NODES) gr = N_NODES - 1;          // tail clamp (guarded write)
        const float* xrow = &x[(size_t)gr * D];
        float4 xv[8];
        #pragma unroll
        for (int kk = 0; kk < 4; ++kk) {
            xv[2 * kk]     = *(const float4*)&xrow[kk * 32 + q * 8];
            xv[2 * kk + 1] = *(const float4*)&xrow[kk * 32 + q * 8 + 4];
        }
        __syncthreads();

        f32x4 acc[8] = {};
        #pragma unroll
        for (int kk = 0; kk < 4; ++kk) {
            union { short8 s; uint32 u[4]; } af;
            float4 a = xv[2 * kk], b = xv[2 * kk + 1];
            af.u[0] = pack2(a.x, a.y); af.u[1] = pack2(a.z, a.w);
            af.u[2] = pack2(b.x, b.y); af.u[3] = pack2(b.z, b.w);
            #pragma unroll
            for (int ct = 0; ct < 8; ++ct) {
                short8 bf = *(const short8*)&Ws[(ct * 16 + cl) * LSTR + kk * 32 + q * 8];
                acc[ct] = __builtin_amdgcn_mfma_f32_16x16x32_bf16(af.s, bf, acc[ct], 0, 0, 0);
            }
        }
        #pragma unroll
        for (int reg = 0; reg < 4; ++reg) {
            int node = g * 64 + wid * 16 + q * 4 + reg;
            if (node < N_NODES) {
                uint32* base = h2 + (size_t)node * 64 + cl;
                #pragma unroll
                for (int ct = 0; ct < 4; ++ct)
                    base[ct * 16] = pack2(acc[ct][reg], acc[ct + 4][reg]);
            }
        }
    }
}

// k2: 8 rows/block (1250 blocks). Scan own bucket's 256 chunk-cells gated by
// cnts (only valid prefixes loaded), LDS-filter into 8 row queues, then the
// proven branch-free depth-8 software-pipelined gather, 2 rows per wave.
__global__ __launch_bounds__(256) void spmm_kernel(
    const uint2* __restrict__ bstore, const int* __restrict__ cnts,
    const int* __restrict__ spillcnt, const uint2* __restrict__ spill,
    const uint32* __restrict__ h2, const float* __restrict__ bias,
    float* __restrict__ out)
{
    __shared__ uint32 qbuf[8 * QPAD2];    // per-row queues (4608 B)
    __shared__ int lcnts[NCHUNK];         // bucket's per-chunk counts (1 KB)
    __shared__ int cnt[8];
    const int t = threadIdx.x;
    const int lane = t & 63;
    const int wid  = t >> 6;
    const int r0 = blockIdx.x * 8;
    const int b  = r0 >> 7;

    lcnts[t] = cnts[b * NCHUNK + t];      // t in [0,256) exactly
    if (t < 8) cnt[t] = 0;
    __syncthreads();

    // scan bucket slice: consecutive i => consecutive addresses (coalesced),
    // loads gated so only the valid prefix of each 768B cell is fetched.
    for (int i = t; i < SLOTS; i += 256) {
        int ch = i / CCAP;
        int sl = i - ch * CCAP;
        if (sl < lcnts[ch]) {
            uint2 e = bstore[(size_t)b * SLOTS + i];
            uint32 d = e.y - (uint32)r0;
            if (d < 8u) {
                int k = atomicAdd(&cnt[d], 1);           // LDS
                if (k < CAP2) qbuf[d * QPAD2 + k] = e.x; // >=CAP2: slow path
            }
        }
    }
    // spill lists (expected all-zero counts; 1KB coalesced read)
    {
        int sc = spillcnt[t];
        for (int k = 0; k < sc; ++k) {                   // ~never
            uint2 e = spill[(size_t)t * SPILLCAP + k];
            uint32 d = e.y - (uint32)r0;
            if (d < 8u) {
                int k2 = atomicAdd(&cnt[d], 1);
                if (k2 < CAP2) qbuf[d * QPAD2 + k2] = e.x;
            }
        }
    }
    __syncthreads();

    for (int half = 0; half < 2; ++half) {
        const int d = wid * 2 + half;
        const int r = r0 + d;
        uint32* qb = &qbuf[d * QPAD2];
        const int ntot = cnt[d];
        float a0 = 0.f, a1 = 0.f;

        if (ntot <= CAP2) {
            if (lane < 16) qb[ntot + lane] = 0;    // zero pad (val=+0.0 recs)
            __builtin_amdgcn_s_waitcnt(0);         // wave-local LDS drain

            const int npad = (ntot + 7) & ~7;
            uint32 rq0,rq1,rq2,rq3,rq4,rq5,rq6,rq7;
            uint32 hh0,hh1,hh2,hh3,hh4,hh5,hh6,hh7;
            rq0 = qb[0]; hh0 = h2[((rq0 & 0xFFFFu) << 6) + lane];
            rq1 = qb[1]; hh1 = h2[((rq1 & 0xFFFFu) << 6) + lane];
            rq2 = qb[2]; hh2 = h2[((rq2 & 0xFFFFu) << 6) + lane];
            rq3 = qb[3]; hh3 = h2[((rq3 & 0xFFFFu) << 6) + lane];
            rq4 = qb[4]; hh4 = h2[((rq4 & 0xFFFFu) << 6) + lane];
            rq5 = qb[5]; hh5 = h2[((rq5 & 0xFFFFu) << 6) + lane];
            rq6 = qb[6]; hh6 = h2[((rq6 & 0xFFFFu) << 6) + lane];
            rq7 = qb[7]; hh7 = h2[((rq7 & 0xFFFFu) << 6) + lane];

#define CONSUME_PREFETCH(RQ, HH, P)                                          \
    {                                                                        \
        a0 = fmaf(__uint_as_float(RQ & 0xFFFF0000u),                         \
                  __uint_as_float(HH << 16), a0);                            \
        a1 = fmaf(__uint_as_float(RQ & 0xFFFF0000u),                         \
                  __uint_as_float(HH & 0xFFFF0000u), a1);                    \
        uint32 rn = qb[j + 8 + P];                                           \
        RQ = rn; HH = h2[((rn & 0xFFFFu) << 6) + lane];                      \
    }

            for (int j = 0; j < npad; j += 8) {
                CONSUME_PREFETCH(rq0, hh0, 0)
                CONSUME_PREFETCH(rq1, hh1, 1)
                CONSUME_PREFETCH(rq2, hh2, 2)
                CONSUME_PREFETCH(rq3, hh3, 3)
                CONSUME_PREFETCH(rq4, hh4, 4)
                CONSUME_PREFETCH(rq5, hh5, 5)
                CONSUME_PREFETCH(rq6, hh6, 6)
                CONSUME_PREFETCH(rq7, hh7, 7)
            }
#undef CONSUME_PREFETCH
        } else {
            // slow path (row > CAP2 edges; +8 sigma, ~never): recompute row
            // from scratch, broadcast-scanning the whole bucket + spills.
            for (int i = 0; i < SLOTS; ++i) {
                int ch = i / CCAP, sl = i - ch * CCAP;
                if (sl < lcnts[ch]) {
                    uint2 e = bstore[(size_t)b * SLOTS + i];
                    if (e.y == (uint32)r) {
                        uint32 hv = h2[((e.x & 0xFFFFu) << 6) + lane];
                        a0 = fmaf(__uint_as_float(e.x & 0xFFFF0000u),
                                  __uint_as_float(hv << 16), a0);
                        a1 = fmaf(__uint_as_float(e.x & 0xFFFF0000u),
                                  __uint_as_float(hv & 0xFFFF0000u), a1);
                    }
                }
            }
            for (int ch = 0; ch < NCHUNK; ++ch) {
                int sc = spillcnt[ch];
                for (int k = 0; k < sc; ++k) {
                    uint2 e = spill[(size_t)ch * SPILLCAP + k];
                    if (e.y == (uint32)r) {
                        uint32 hv = h2[((e.x & 0xFFFFu) << 6) + lane];
                        a0 = fmaf(__uint_as_float(e.x & 0xFFFF0000u),
                                  __uint_as_float(hv << 16), a0);
                        a1 = fmaf(__uint_as_float(e.x & 0xFFFF0000u),
                                  __uint_as_float(hv & 0xFFFF0000u), a1);
                    }
                }
            }
        }

        out[(size_t)r * D + lane]      = a0 + bias[lane];
        out[(size_t)r * D + 64 + lane] = a1 + bias[lane + 64];
    }
}

extern "C" void kernel_launch(void* const* d_in, const int* in_sizes, int n_in,
                              void* d_out, int out_size, void* d_ws, size_t ws_size,
                              hipStream_t stream)
{
    const float* x    = (const float*)d_in[0];
    const float* aval = (const float*)d_in[1];
    const float* w    = (const float*)d_in[2];
    const float* bias = (const float*)d_in[3];
    const int* arow   = (const int*)d_in[4];
    const int* acol   = (const int*)d_in[5];

    char* ws = (char*)d_ws;
    uint32* h2       = (uint32*)(ws);              //  2,560,000 B
    int*    cnts     = (int*)(ws + 2560000);       //     80,896 B (79 x 256)
    int*    spillcnt = (int*)(ws + 2640896);       //      1,024 B (256)
    uint2*  bstore   = (uint2*)(ws + 2641920);     // 15,532,032 B (79x256x96x8)
    uint2*  spill    = (uint2*)(ws + 18173952);    //  5,120,000 B (256x2500x8)

    // no memset: cnts/spillcnt are written unconditionally by k1

    gemm_scatter_kernel<<<GRID1, 256, 0, stream>>>(
        x, w, arow, acol, aval, h2, cnts, spillcnt, bstore, spill);
    spmm_kernel<<<N_NODES / 8, 256, 0, stream>>>(
        bstore, cnts, spillcnt, spill, h2, bias, (float*)d_out);
}

// Round 5
// 103.662 us; speedup vs baseline: 1.1908x; 1.1908x over previous
//
#include <hip/hip_runtime.h>

#define N_NODES 10000
#define N_EDGES 640000
#define D 128
#define NQ (N_EDGES / 4)      // 160000 edge quads

#define NCHUNK 128            // scatter chunks (= scatter blocks)
#define QPC (NQ / NCHUNK)     // 1250 quads (5000 edges) per chunk, exact
#define GEMM_BLOCKS 157       // 64 nodes per block (MFMA)
#define GRID1 (NCHUNK + GEMM_BLOCKS)   // 285
#define NBUCK 625             // bucket = row >> 4 (16 rows per bucket, exact)
#define CCAP 24               // per (bucket,chunk) cell cap: mean 8, +5.7 sigma
#define BSLOTS (NCHUNK * CCAP)// 3072 slots per bucket
#define SPILLCAP 5000         // worst case: a chunk spills every edge
#define CAP2 128              // per-row queue cap (mean 64, +8 sigma; slow path)
#define QPAD2 144             // CAP2 + 16 zero-pad
#define LSTR 136              // LDS row stride in ushorts (272B)

typedef unsigned int uint32;
typedef unsigned short u16;
using short8 = __attribute__((ext_vector_type(8))) short;
using f32x4  = __attribute__((ext_vector_type(4))) float;

__device__ __forceinline__ uint32 f2bf_bits(float f) {
    uint32 u = __float_as_uint(f);
    return (u + 0x7FFFu + ((u >> 16) & 1u)) >> 16;   // RNE bf16 bits
}
__device__ __forceinline__ uint32 pack2(float lo, float hi) {
    return f2bf_bits(lo) | (f2bf_bits(hi) << 16);
}

// R13: R12 showed spmm=51us and the cause: 128-row buckets scanned by 8-row
// blocks => every record read 16x in a branchy load->compare->LDS-atomic
// chain. Fix: 16-row buckets (NBUCK=625) so an 8-row k2 block scans only its
// own bucket (amplification 16x -> 2x, 3072 gated slots vs 24576). k1 keeps
// LDS-only binning, unconditional count writes (no memset), no global atomics.
__global__ __launch_bounds__(256, 4) void gemm_scatter_kernel(
    const float* __restrict__ x, const float* __restrict__ w,
    const int* __restrict__ row, const int* __restrict__ col,
    const float* __restrict__ val,
    uint32* __restrict__ h2, int* __restrict__ cnts,
    int* __restrict__ spillcnt, uint2* __restrict__ bstore,
    uint2* __restrict__ spill)
{
    __shared__ __align__(16) u16 Ws[128 * LSTR];   // 34816 B (scatter aliases)
    const int t = threadIdx.x;

    if (blockIdx.x < NCHUNK) {
        // ---- chunk scatter: single pass, LDS counters only ----
        int* lcnt = (int*)Ws;             // [0..624] bucket counts, [625] spill
        for (int i = t; i <= NBUCK; i += 256) lcnt[i] = 0;
        __syncthreads();

        const int sb = blockIdx.x;
        const int4*   row4 = (const int4*)row;
        const int4*   col4 = (const int4*)col;
        const float4* val4 = (const float4*)val;
        const int i0 = sb * QPC;
        for (int i = i0 + t; i < i0 + QPC; i += 256) {
            int4 r = row4[i]; int4 c = col4[i]; float4 v = val4[i];
            #pragma unroll
            for (int e = 0; e < 4; ++e) {
                int rr = (e == 0) ? r.x : (e == 1) ? r.y : (e == 2) ? r.z : r.w;
                int cc = (e == 0) ? c.x : (e == 1) ? c.y : (e == 2) ? c.z : c.w;
                float vv = (e == 0) ? v.x : (e == 1) ? v.y : (e == 2) ? v.z : v.w;
                uint32 rc = (uint32)cc | (f2bf_bits(vv) << 16);
                int b = rr >> 4;
                int k = atomicAdd(&lcnt[b], 1);            // LDS only
                if (k < CCAP)
                    bstore[(size_t)(b * NCHUNK + sb) * CCAP + k] =
                        make_uint2(rc, (uint32)rr);
                else {                                     // +5.7 sigma, ~never
                    int ks = atomicAdd(&lcnt[NBUCK], 1);
                    spill[(size_t)sb * SPILLCAP + ks] = make_uint2(rc, (uint32)rr);
                }
            }
        }
        __syncthreads();
        for (int b = t; b < NBUCK; b += 256) {
            int c = lcnt[b];
            cnts[b * NCHUNK + sb] = (c < CCAP) ? c : CCAP;  // unconditional
        }
        if (t == 0) spillcnt[sb] = lcnt[NBUCK];             // unconditional
    } else {
        // ---- MFMA GEMM: 64 rows/block, 4 waves x 16 rows x 128 cols.
        // A direct global->reg; W staged col-major in LDS (float4 loads).
        // C/D: col=lane&15, row=quad*4+reg (HW-verified).
        const int g = blockIdx.x - NCHUNK;
        const int lane = t & 63;
        const int wid  = t >> 6;
        const int q = lane >> 4, cl = lane & 15;

        const float4* w4 = (const float4*)w;
        #pragma unroll
        for (int i = 0; i < 8; ++i) {                 // stage W^T (128x128)
            int lin = t + i * 256;                    // m(k-pair) x qc(col-quad)
            int m  = lin >> 5;
            int qc = lin & 31;
            float4 r0 = w4[(2 * m) * 32 + qc];        // row 2m, cols 4qc..4qc+3
            float4 r1 = w4[(2 * m + 1) * 32 + qc];
            int c = qc * 4;
            *(uint32*)&Ws[(c + 0) * LSTR + 2 * m] = pack2(r0.x, r1.x);
            *(uint32*)&Ws[(c + 1) * LSTR + 2 * m] = pack2(r0.y, r1.y);
            *(uint32*)&Ws[(c + 2) * LSTR + 2 * m] = pack2(r0.z, r1.z);
            *(uint32*)&Ws[(c + 3) * LSTR + 2 * m] = pack2(r0.w, r1.w);
        }

        int gr = g * 64 + wid * 16 + cl;              // A-fragment row
        if (gr >= N_NODES) gr = N_NODES - 1;          // tail clamp (guarded write)
        const float* xrow = &x[(size_t)gr * D];
        float4 xv[8];
        #pragma unroll
        for (int kk = 0; kk < 4; ++kk) {
            xv[2 * kk]     = *(const float4*)&xrow[kk * 32 + q * 8];
            xv[2 * kk + 1] = *(const float4*)&xrow[kk * 32 + q * 8 + 4];
        }
        __syncthreads();

        f32x4 acc[8] = {};
        #pragma unroll
        for (int kk = 0; kk < 4; ++kk) {
            union { short8 s; uint32 u[4]; } af;
            float4 a = xv[2 * kk], b = xv[2 * kk + 1];
            af.u[0] = pack2(a.x, a.y); af.u[1] = pack2(a.z, a.w);
            af.u[2] = pack2(b.x, b.y); af.u[3] = pack2(b.z, b.w);
            #pragma unroll
            for (int ct = 0; ct < 8; ++ct) {
                short8 bf = *(const short8*)&Ws[(ct * 16 + cl) * LSTR + kk * 32 + q * 8];
                acc[ct] = __builtin_amdgcn_mfma_f32_16x16x32_bf16(af.s, bf, acc[ct], 0, 0, 0);
            }
        }
        #pragma unroll
        for (int reg = 0; reg < 4; ++reg) {
            int node = g * 64 + wid * 16 + q * 4 + reg;
            if (node < N_NODES) {
                uint32* base = h2 + (size_t)node * 64 + cl;
                #pragma unroll
                for (int ct = 0; ct < 4; ++ct)
                    base[ct * 16] = pack2(acc[ct][reg], acc[ct + 4][reg]);
            }
        }
    }
}

// k2: 8 rows/block = half a 16-row bucket (1250 blocks). Scan ONLY own
// bucket's 3072 slots gated by cnts (valid prefixes only), LDS-filter into
// 8 row queues, then the proven branch-free depth-8 software-pipelined
// gather (8 L2 gathers in flight), 2 rows per wave.
__global__ __launch_bounds__(256) void spmm_kernel(
    const uint2* __restrict__ bstore, const int* __restrict__ cnts,
    const int* __restrict__ spillcnt, const uint2* __restrict__ spill,
    const uint32* __restrict__ h2, const float* __restrict__ bias,
    float* __restrict__ out)
{
    __shared__ uint32 qbuf[8 * QPAD2];    // per-row queues (4608 B)
    __shared__ int lcnts[NCHUNK];         // bucket's per-chunk counts (512 B)
    __shared__ int cnt[8];
    const int t = threadIdx.x;
    const int lane = t & 63;
    const int wid  = t >> 6;
    const int r0 = blockIdx.x * 8;
    const int b  = r0 >> 4;               // 16-row bucket

    if (t < NCHUNK) lcnts[t] = cnts[b * NCHUNK + t];
    if (t < 8) cnt[t] = 0;
    __syncthreads();

    // scan own bucket: consecutive i => consecutive addresses (coalesced),
    // loads gated so only the valid prefix of each 192B cell is fetched.
    const size_t sbase = (size_t)b * BSLOTS;
    for (int i = t; i < BSLOTS; i += 256) {
        int ch = i / CCAP;
        int sl = i - ch * CCAP;
        if (sl < lcnts[ch]) {
            uint2 e = bstore[sbase + i];
            uint32 d = e.y - (uint32)r0;
            if (d < 8u) {
                int k = atomicAdd(&cnt[d], 1);           // LDS
                if (k < CAP2) qbuf[d * QPAD2 + k] = e.x; // >=CAP2: slow path
            }
        }
    }
    // spill lists (expected all-zero counts)
    if (t < NCHUNK) {
        int sc = spillcnt[t];
        for (int k = 0; k < sc; ++k) {                   // ~never
            uint2 e = spill[(size_t)t * SPILLCAP + k];
            uint32 d = e.y - (uint32)r0;
            if (d < 8u) {
                int k2 = atomicAdd(&cnt[d], 1);
                if (k2 < CAP2) qbuf[d * QPAD2 + k2] = e.x;
            }
        }
    }
    __syncthreads();

    for (int half = 0; half < 2; ++half) {
        const int d = wid * 2 + half;
        const int r = r0 + d;
        uint32* qb = &qbuf[d * QPAD2];
        const int ntot = cnt[d];
        float a0 = 0.f, a1 = 0.f;

        if (ntot <= CAP2) {
            if (lane < 16) qb[ntot + lane] = 0;    // zero pad (val=+0.0 recs)
            __builtin_amdgcn_s_waitcnt(0);         // wave-local LDS drain

            const int npad = (ntot + 7) & ~7;
            uint32 rq0,rq1,rq2,rq3,rq4,rq5,rq6,rq7;
            uint32 hh0,hh1,hh2,hh3,hh4,hh5,hh6,hh7;
            rq0 = qb[0]; hh0 = h2[((rq0 & 0xFFFFu) << 6) + lane];
            rq1 = qb[1]; hh1 = h2[((rq1 & 0xFFFFu) << 6) + lane];
            rq2 = qb[2]; hh2 = h2[((rq2 & 0xFFFFu) << 6) + lane];
            rq3 = qb[3]; hh3 = h2[((rq3 & 0xFFFFu) << 6) + lane];
            rq4 = qb[4]; hh4 = h2[((rq4 & 0xFFFFu) << 6) + lane];
            rq5 = qb[5]; hh5 = h2[((rq5 & 0xFFFFu) << 6) + lane];
            rq6 = qb[6]; hh6 = h2[((rq6 & 0xFFFFu) << 6) + lane];
            rq7 = qb[7]; hh7 = h2[((rq7 & 0xFFFFu) << 6) + lane];

#define CONSUME_PREFETCH(RQ, HH, P)                                          \
    {                                                                        \
        a0 = fmaf(__uint_as_float(RQ & 0xFFFF0000u),                         \
                  __uint_as_float(HH << 16), a0);                            \
        a1 = fmaf(__uint_as_float(RQ & 0xFFFF0000u),                         \
                  __uint_as_float(HH & 0xFFFF0000u), a1);                    \
        uint32 rn = qb[j + 8 + P];                                           \
        RQ = rn; HH = h2[((rn & 0xFFFFu) << 6) + lane];                      \
    }

            for (int j = 0; j < npad; j += 8) {
                CONSUME_PREFETCH(rq0, hh0, 0)
                CONSUME_PREFETCH(rq1, hh1, 1)
                CONSUME_PREFETCH(rq2, hh2, 2)
                CONSUME_PREFETCH(rq3, hh3, 3)
                CONSUME_PREFETCH(rq4, hh4, 4)
                CONSUME_PREFETCH(rq5, hh5, 5)
                CONSUME_PREFETCH(rq6, hh6, 6)
                CONSUME_PREFETCH(rq7, hh7, 7)
            }
#undef CONSUME_PREFETCH
        } else {
            // slow path (row > CAP2 edges; +8 sigma, ~never): rescan bucket
            // + all spills for this row only.
            for (int i = 0; i < BSLOTS; ++i) {
                int ch = i / CCAP, sl = i - ch * CCAP;
                if (sl < lcnts[ch]) {
                    uint2 e = bstore[sbase + i];
                    if (e.y == (uint32)r) {
                        uint32 hv = h2[((e.x & 0xFFFFu) << 6) + lane];
                        a0 = fmaf(__uint_as_float(e.x & 0xFFFF0000u),
                                  __uint_as_float(hv << 16), a0);
                        a1 = fmaf(__uint_as_float(e.x & 0xFFFF0000u),
                                  __uint_as_float(hv & 0xFFFF0000u), a1);
                    }
                }
            }
            for (int ch = 0; ch < NCHUNK; ++ch) {
                int sc = spillcnt[ch];
                for (int k = 0; k < sc; ++k) {
                    uint2 e = spill[(size_t)ch * SPILLCAP + k];
                    if (e.y == (uint32)r) {
                        uint32 hv = h2[((e.x & 0xFFFFu) << 6) + lane];
                        a0 = fmaf(__uint_as_float(e.x & 0xFFFF0000u),
                                  __uint_as_float(hv << 16), a0);
                        a1 = fmaf(__uint_as_float(e.x & 0xFFFF0000u),
                                  __uint_as_float(hv & 0xFFFF0000u), a1);
                    }
                }
            }
        }

        out[(size_t)r * D + lane]      = a0 + bias[lane];
        out[(size_t)r * D + 64 + lane] = a1 + bias[lane + 64];
    }
}

extern "C" void kernel_launch(void* const* d_in, const int* in_sizes, int n_in,
                              void* d_out, int out_size, void* d_ws, size_t ws_size,
                              hipStream_t stream)
{
    const float* x    = (const float*)d_in[0];
    const float* aval = (const float*)d_in[1];
    const float* w    = (const float*)d_in[2];
    const float* bias = (const float*)d_in[3];
    const int* arow   = (const int*)d_in[4];
    const int* acol   = (const int*)d_in[5];

    char* ws = (char*)d_ws;
    uint32* h2       = (uint32*)(ws);              //  2,560,000 B
    int*    cnts     = (int*)(ws + 2560000);       //    320,000 B (625 x 128)
    int*    spillcnt = (int*)(ws + 2880000);       //        512 B (128)
    uint2*  bstore   = (uint2*)(ws + 2880512);     // 15,360,000 B (625x128x24x8)
    uint2*  spill    = (uint2*)(ws + 18240512);    //  5,120,000 B (128x5000x8)
    // total 23,360,512 B; no memset: cnts/spillcnt written unconditionally

    gemm_scatter_kernel<<<GRID1, 256, 0, stream>>>(
        x, w, arow, acol, aval, h2, cnts, spillcnt, bstore, spill);
    spmm_kernel<<<N_NODES / 8, 256, 0, stream>>>(
        bstore, cnts, spillcnt, spill, h2, bias, (float*)d_out);
}